// Round 7
// baseline (490.937 us; speedup 1.0000x reference)
//
#include <hip/hip_runtime.h>
#include <hip/hip_bf16.h>

// DropLearner: per-edge gumbel-sigmoid gate + top-80% select + sym degree norm.
//
// Pipeline (5 dispatches):
//   1. init_kernel : zero rowsum+hists, zero state, detect int32/int64 indices
//   2. gate_kernel : gate[e]->d_out, atomicAdd rowsum[row] (ALL edges: dropped
//                    gates are ~4e-9, invisible through the dinv clamp),
//                    LDS hist of top-11 bits, last block runs radix scan 0
//   3. hist1_kernel: refine bits [20:10], last block runs scan 1
//   4. hist2_kernel: refine bits [9:0],  last block runs scan 2 (exact k-th)
//   5. values_kernel: d_out[e] = kept ? gate * f(rowsum[r]) * f(rowsum[c]) : 0
//                    with f(rs) = rs>0 ? min(rs^-0.5,10) : 10 computed inline.
//
// state[]: 0=threshold bits, 1=kRem, 2=ctr_gate, 3=is64, 4=ctr_h1, 5=ctr_h2

#define BIASF 0.0001f
#define H_DIM 128

__device__ __forceinline__ int load_idx(const void* ei, long long pos, int is64) {
    if (is64) return (int)((const long long*)ei)[pos];
    return ((const int*)ei)[pos];
}

// last-block radix scan: find bin b with cnt(>b) < kRem <= cnt(>=b)
__device__ void scan_finalize(unsigned* hist, int nb, int shift,
                              unsigned kRem, unsigned pfx, unsigned* state) {
    const int C = nb / 256;            // 8 or 4
    __shared__ unsigned csum[256];
    __shared__ unsigned sfx[256];
    const int t = threadIdx.x;
    unsigned vals[8];
    unsigned s = 0;
    for (int i = 0; i < C; ++i) {
        vals[i] = atomicAdd(&hist[t * C + i], 0u);  // coherent read
        s += vals[i];
    }
    csum[t] = s;
    __syncthreads();
    if (t == 0) {
        unsigned acc = 0;
        for (int i = 255; i >= 0; --i) { sfx[i] = acc; acc += csum[i]; }
    }
    __syncthreads();
    unsigned g = sfx[t];               // count strictly above this chunk
    for (int j = C - 1; j >= 0; --j) {
        unsigned cb = vals[j];
        if (g < kRem && g + cb >= kRem) {
            state[0] = pfx | ((unsigned)(t * C + j) << shift);
            state[1] = kRem - g;
        }
        g += cb;
    }
}

// ------------------------------------------------------------------- init
__global__ __launch_bounds__(256) void init_kernel(
    unsigned* __restrict__ zbase, long long zwords,
    const unsigned* __restrict__ ei32, unsigned* __restrict__ state) {
    long long i = (long long)blockIdx.x * 256 + threadIdx.x;
    const long long stride = (long long)gridDim.x * 256;
    for (; i < zwords; i += stride) zbase[i] = 0u;
    if (blockIdx.x == 0 && threadIdx.x == 0) {
        for (int j = 0; j < 8; ++j) state[j] = 0u;
        unsigned orall = 0;
        for (int j = 0; j < 64; ++j) orall |= ei32[2 * j + 1];
        state[3] = (orall == 0u) ? 1u : 0u;   // int64 with zero hi-words
    }
}

// ------------------------------------------------------------------- gate
// half-wave (32 lanes) per edge, 2 edges per half-wave per iteration.
__global__ __launch_bounds__(256) void gate_kernel(
    const float* __restrict__ x, const void* __restrict__ ei,
    const float* __restrict__ noise, float* __restrict__ gate_out,
    float* __restrict__ rowsum, unsigned* __restrict__ hist0,
    unsigned* __restrict__ state, long long E, unsigned k0) {
    __shared__ unsigned lhist[2048];
    for (int i = threadIdx.x; i < 2048; i += 256) lhist[i] = 0;
    __syncthreads();
    const int is64 = (int)state[3];
    const int hw   = threadIdx.x >> 5;
    const int lane = threadIdx.x & 31;
    const long long step = (long long)gridDim.x * 16;

    for (long long base = (long long)blockIdx.x * 16 + hw * 2; base < E;
         base += step) {
        const bool v1 = (base + 1 < E);
        int r0 = load_idx(ei, base, is64);
        int c0 = load_idx(ei, E + base, is64);
        int r1 = v1 ? load_idx(ei, base + 1, is64) : r0;
        int c1 = v1 ? load_idx(ei, E + base + 1, is64) : c0;
        // start noise-side math early (2 lanes) to overlap with gathers
        float lnz = 0.0f;
        if (lane < 2 && base + lane < E) {
            float nz  = noise[base + lane];
            float eps = (BIASF - (1.0f - BIASF)) * nz + (1.0f - BIASF);
            lnz = logf(eps) - logf(1.0f - eps);
        }
        float4 a0 = ((const float4*)(x + (long long)r0 * H_DIM))[lane];
        float4 b0 = ((const float4*)(x + (long long)c0 * H_DIM))[lane];
        float4 a1 = ((const float4*)(x + (long long)r1 * H_DIM))[lane];
        float4 b1 = ((const float4*)(x + (long long)c1 * H_DIM))[lane];
        float p0 = a0.x * b0.x + a0.y * b0.y + a0.z * b0.z + a0.w * b0.w;
        float p1 = a1.x * b1.x + a1.y * b1.y + a1.z * b1.z + a1.w * b1.w;
        #pragma unroll
        for (int off = 16; off; off >>= 1) {
            p0 += __shfl_xor(p0, off);
            p1 += __shfl_xor(p1, off);
        }
        if (lane < 2 && base + lane < E) {
            const long long e = base + lane;
            const float p = (lane == 0) ? p0 : p1;
            const int   rr = (lane == 0) ? r0 : r1;
            float s = (lnz + p) * 2.0f;         // / TEMP_DE (=0.5)
            float gate;
            if (s >= 0.0f) {
                gate = 1.0f / (1.0f + expf(-s));
            } else {
                float ez = expf(s);
                gate = ez / (1.0f + ez);
            }
            gate_out[e] = gate;
            atomicAdd(&rowsum[rr], gate);
            atomicAdd(&lhist[__float_as_uint(gate) >> 21], 1u);
        }
    }
    __syncthreads();
    for (int i = threadIdx.x; i < 2048; i += 256) {
        unsigned v = lhist[i];
        if (v) atomicAdd(&hist0[i], v);
    }
    __threadfence();
    __shared__ unsigned isLast;
    if (threadIdx.x == 0)
        isLast = (atomicAdd(&state[2], 1u) == (unsigned)gridDim.x - 1u);
    __syncthreads();
    if (isLast) scan_finalize(hist0, 2048, 21, k0, 0u, state);
}

// ----------------------------------------------------- refine histograms
template <int LEVEL>
__global__ __launch_bounds__(256) void hist_kernel(
    const float* __restrict__ gate, unsigned* __restrict__ hist,
    unsigned* __restrict__ state, long long E4, long long E) {
    __shared__ unsigned lh[2048];
    const int nb = (LEVEL == 1) ? 2048 : 1024;
    for (int i = threadIdx.x; i < nb; i += 256) lh[i] = 0;
    __syncthreads();
    const unsigned pfx  = state[0];
    const unsigned kRem = state[1];
    const long long stride = (long long)gridDim.x * 256;
    for (long long q = (long long)blockIdx.x * 256 + threadIdx.x; q < E4;
         q += stride) {
        float4 g4 = ((const float4*)gate)[q];
        float gv[4] = {g4.x, g4.y, g4.z, g4.w};
        #pragma unroll
        for (int j = 0; j < 4; ++j) {
            unsigned key = __float_as_uint(gv[j]);
            if (LEVEL == 1) {
                if ((key >> 21) == (pfx >> 21))
                    atomicAdd(&lh[(key >> 10) & 2047], 1u);
            } else {
                if ((key >> 10) == (pfx >> 10))
                    atomicAdd(&lh[key & 1023], 1u);
            }
        }
    }
    if (blockIdx.x == 0) {  // scalar tail (E not multiple of 4)
        for (long long e = E4 * 4 + threadIdx.x; e < E; e += 256) {
            unsigned key = __float_as_uint(gate[e]);
            if (LEVEL == 1) {
                if ((key >> 21) == (pfx >> 21))
                    atomicAdd(&lh[(key >> 10) & 2047], 1u);
            } else {
                if ((key >> 10) == (pfx >> 10))
                    atomicAdd(&lh[key & 1023], 1u);
            }
        }
    }
    __syncthreads();
    for (int i = threadIdx.x; i < nb; i += 256) {
        unsigned v = lh[i];
        if (v) atomicAdd(&hist[i], v);
    }
    __threadfence();
    __shared__ unsigned isLast;
    if (threadIdx.x == 0)
        isLast = (atomicAdd(&state[LEVEL == 1 ? 4 : 5], 1u) ==
                  (unsigned)gridDim.x - 1u);
    __syncthreads();
    if (isLast)
        scan_finalize(hist, nb, (LEVEL == 1) ? 10 : 0, kRem, pfx, state);
}

// ----------------------------------------------------------------- values
__device__ __forceinline__ float dinv_of(float rs) {
    return (rs > 0.0f) ? fminf(1.0f / sqrtf(rs), 10.0f) : 10.0f;
}

__global__ __launch_bounds__(256) void values_kernel(
    float* __restrict__ gate_io, const void* __restrict__ ei,
    const unsigned* __restrict__ state, const float* __restrict__ rowsum,
    long long E4, long long E) {
    const unsigned tbits = state[0];
    const int is64 = (int)state[3];
    const long long stride = (long long)gridDim.x * 256;
    for (long long q = (long long)blockIdx.x * 256 + threadIdx.x; q < E4;
         q += stride) {
        float4 g4 = ((const float4*)gate_io)[q];
        float gv[4] = {g4.x, g4.y, g4.z, g4.w};
        float ov[4];
        #pragma unroll
        for (int j = 0; j < 4; ++j) {
            long long e = q * 4 + j;
            float v = 0.0f;
            if (__float_as_uint(gv[j]) >= tbits) {
                int r = load_idx(ei, e, is64);
                int c = load_idx(ei, E + e, is64);
                v = gv[j] * dinv_of(rowsum[r]) * dinv_of(rowsum[c]);
            }
            ov[j] = v;
        }
        ((float4*)gate_io)[q] = make_float4(ov[0], ov[1], ov[2], ov[3]);
    }
    if (blockIdx.x == 0) {  // scalar tail
        for (long long e = E4 * 4 + threadIdx.x; e < E; e += 256) {
            float gv = gate_io[e];
            float v = 0.0f;
            if (__float_as_uint(gv) >= tbits) {
                int r = load_idx(ei, e, is64);
                int c = load_idx(ei, E + e, is64);
                v = gv * dinv_of(rowsum[r]) * dinv_of(rowsum[c]);
            }
            gate_io[e] = v;
        }
    }
}

extern "C" void kernel_launch(void* const* d_in, const int* in_sizes, int n_in,
                              void* d_out, int out_size, void* d_ws, size_t ws_size,
                              hipStream_t stream) {
    const float* x     = (const float*)d_in[0];
    const void*  ei    = d_in[1];
    const float* noise = (const float*)d_in[2];
    float* out = (float*)d_out;

    const long long N  = (long long)in_sizes[0] / H_DIM;
    const long long E  = (long long)in_sizes[1] / 2;
    const long long E4 = E / 4;
    const unsigned  k  = (unsigned)((double)E * 0.8);  // KEEP_FRAC

    // workspace: rowsum[N] hist0[2048] hist1[2048] hist2[1024] | state[8]
    float*    rowsum = (float*)d_ws;
    unsigned* hist0  = (unsigned*)(rowsum + N);
    unsigned* hist1  = hist0 + 2048;
    unsigned* hist2  = hist1 + 2048;
    unsigned* state  = hist2 + 1024;
    (void)ws_size; (void)n_in; (void)out_size;

    const long long zwords = N + 2048 + 2048 + 1024;
    int iblocks = (int)((zwords + 255) / 256);
    init_kernel<<<iblocks, 256, 0, stream>>>((unsigned*)d_ws, zwords,
                                             (const unsigned*)ei, state);

    int gblocks = (int)(((E + 15) / 16 < 2048) ? (E + 15) / 16 : 2048);
    gate_kernel<<<gblocks, 256, 0, stream>>>(x, ei, noise, out, rowsum, hist0,
                                             state, E, k);

    int hblocks = (int)(((E4 + 255) / 256 < 1024) ? (E4 + 255) / 256 : 1024);
    hist_kernel<1><<<hblocks, 256, 0, stream>>>(out, hist1, state, E4, E);
    hist_kernel<2><<<hblocks, 256, 0, stream>>>(out, hist2, state, E4, E);

    values_kernel<<<hblocks, 256, 0, stream>>>(out, ei, state, rowsum, E4, E);
}